// Round 12
// baseline (838.951 us; speedup 1.0000x reference)
//
#include <hip/hip_runtime.h>
#include <hip/hip_bf16.h>

#define N_NODES 50000
#define N_EDGES 800000
#define FDIM 64
#define NBUCK 391          // ceil(50000/128) buckets of 128 nodes
#define PAD 16             // one counter per 64B line

typedef __attribute__((ext_vector_type(8))) short short8;
typedef __attribute__((ext_vector_type(4))) float f32x4;

// fp32 -> bf16 bits, round-to-nearest-even
__device__ __forceinline__ unsigned f2bf(float f) {
    unsigned u = __float_as_uint(f);
    u += 0x7fffu + ((u >> 16) & 1u);
    return u >> 16;
}
__device__ __forceinline__ float bf2f_lo(unsigned u) { return __uint_as_float(u << 16); }
__device__ __forceinline__ float bf2f_hi(unsigned u) { return __uint_as_float(u & 0xffff0000u); }

// exclusive scan of one value per thread across a 256-thread block
__device__ __forceinline__ int excl_scan_256(int v, int* wtot, int* wincl) {
    const int t = threadIdx.x, lane = t & 63, w = t >> 6;
    int sv = v;
#pragma unroll
    for (int off = 1; off < 64; off <<= 1) {
        int u = __shfl_up(sv, off, 64);
        if (lane >= off) sv += u;
    }
    if (lane == 63) wtot[w] = sv;
    __syncthreads();
    if (w == 0 && lane < 4) {
        int incl = 0;
#pragma unroll
        for (int k = 0; k < 4; ++k)
            if (k <= lane) incl += wtot[k];
        wincl[lane] = incl;
    }
    __syncthreads();
    return (w ? wincl[w - 1] : 0) + sv - v;
}

// ---------------------------------------------------------------------------
// preprocess (fused): [0,3124] convert x0->bf16; [3125,3128] pack weights;
// [3129,3910] bucket histogram of dst>>7 (LDS-aggregated, padded counters).
// ---------------------------------------------------------------------------
__global__ __launch_bounds__(256)
void preprocess_kernel(const float* __restrict__ x0, unsigned short* __restrict__ x_bf,
                       const float* __restrict__ Wl0, const float* __restrict__ Wr0,
                       const float* __restrict__ Wl1, const float* __restrict__ Wr1,
                       unsigned short* __restrict__ pW,
                       const int* __restrict__ dst, int* __restrict__ bc_pad) {
    const int b = blockIdx.x;
    const int t = threadIdx.x;
    if (b < 3125) {                       // convert: 3125*256*4 = 3.2M exactly
        int i = (b * 256 + t) * 4;
        float4 v = *(const float4*)(x0 + i);
        uint2 o;
        o.x = f2bf(v.x) | (f2bf(v.y) << 16);
        o.y = f2bf(v.z) | (f2bf(v.w) << 16);
        *(uint2*)(x_bf + i) = o;
    } else if (b < 3129) {                // pack W into MFMA B-fragment order
        const float* Wsrc[4] = {Wl0, Wr0, Wl1, Wr1};
        const float* W = Wsrc[b - 3125];
        unsigned short* P = pW + (b - 3125) * FDIM * FDIM;
        for (int idx = t; idx < FDIM * FDIM; idx += 256) {
            int j = idx & 7;
            int lane = (idx >> 3) & 63;
            int g = idx >> 9;             // ct*2 + kk
            int ct = g >> 1, kk = g & 1;
            int k = kk * 32 + ((lane >> 4) & 3) * 8 + j;
            int col = ct * 16 + (lane & 15);
            P[idx] = (unsigned short)f2bf(W[k * FDIM + col]);
        }
    } else {                              // histogram: 782 blocks x 1024 edges
        __shared__ int h[NBUCK];
        for (int j = t; j < NBUCK; j += 256) h[j] = 0;
        __syncthreads();
        int e0 = (b - 3129) * 1024;
#pragma unroll
        for (int k = 0; k < 4; ++k) {
            int e = e0 + k * 256 + t;
            if (e < N_EDGES) atomicAdd(&h[dst[e] >> 7], 1);
        }
        __syncthreads();
        for (int j = t; j < NBUCK; j += 256) {
            int c = h[j];
            if (c) atomicAdd(&bc_pad[j * PAD], c);
        }
    }
}

// ---------------------------------------------------------------------------
// bucket scatter: rank edges per bucket in LDS, reserve space with one padded
// global atomic per (block,bucket), write packed (dst<<16)|src to ebuf.
// ---------------------------------------------------------------------------
__global__ __launch_bounds__(256)
void bucket_scatter_kernel(const int* __restrict__ src, const int* __restrict__ dst,
                           const int* __restrict__ bc_pad, int* __restrict__ cur_pad,
                           unsigned* __restrict__ ebuf) {
    __shared__ int sEx[NBUCK + 1];
    __shared__ int h[NBUCK];
    __shared__ int base[NBUCK];
    __shared__ int wtot[4], wincl[4];
    __shared__ int chunk_tot;
    const int t = threadIdx.x;

    // exclusive scan over 391 bucket counts (2 chunks of 256)
    int v0 = (t < NBUCK) ? bc_pad[t * PAD] : 0;
    int ex0 = excl_scan_256(v0, wtot, wincl);
    sEx[t] = ex0;
    if (t == 255) chunk_tot = ex0 + v0;
    __syncthreads();
    int idx1 = 256 + t;
    int v1 = (idx1 < NBUCK) ? bc_pad[idx1 * PAD] : 0;
    int ex1 = excl_scan_256(v1, wtot, wincl);
    if (idx1 <= NBUCK) sEx[idx1] = chunk_tot + ex1;
    for (int j = t; j < NBUCK; j += 256) h[j] = 0;
    __syncthreads();

    int e0 = blockIdx.x * 1024;
    int bk[4], rk[4]; unsigned pk[4];
#pragma unroll
    for (int k = 0; k < 4; ++k) {
        int e = e0 + k * 256 + t;
        if (e < N_EDGES) {
            int d = dst[e];
            bk[k] = d >> 7;
            pk[k] = ((unsigned)d << 16) | (unsigned)src[e];
            rk[k] = atomicAdd(&h[bk[k]], 1);
        } else bk[k] = -1;
    }
    __syncthreads();
    for (int j = t; j < NBUCK; j += 256) {
        int c = h[j];
        base[j] = c ? (sEx[j] + atomicAdd(&cur_pad[j * PAD], c)) : 0;
    }
    __syncthreads();
#pragma unroll
    for (int k = 0; k < 4; ++k)
        if (bk[k] >= 0) ebuf[base[bk[k]] + rk[k]] = pk[k];
}

// ---------------------------------------------------------------------------
// fused SAGE layer via bucket-local LDS accumulation. One block per bucket
// (128 nodes), 512 threads. Edge phase: each edge adds its src row (bf16->f32)
// into acc[dst&127] via ds_add_f32; row-rotated layout phys_col=(col+row)&63
// spreads banks (~2-way). Then MFMA transform from LDS:
// out = relu( ((acc+self)/(cnt+1)) @ Wl + bl + self @ Wr ).
// A[m=lane&15][k=(lane>>4)*8+j]; C/D: col=lane&15, row=(lane>>4)*4+reg.
// ---------------------------------------------------------------------------
template <bool OUT_BF16>
__global__ __launch_bounds__(512)
void sage_accum_kernel(const unsigned short* __restrict__ xb,
                       const unsigned* __restrict__ ebuf,
                       const int* __restrict__ bc_pad,
                       const unsigned short* __restrict__ pWl,
                       const float* __restrict__ bl,
                       const unsigned short* __restrict__ pWr,
                       float* __restrict__ out_f32,
                       unsigned short* __restrict__ out_bf) {
    __shared__ float acc[128 * FDIM];   // row-rotated: [row*64 + ((col+row)&63)]
    __shared__ int cnt[128];
    __shared__ int sEx[NBUCK + 1];

    const int t = threadIdx.x;
    const int w = t >> 6;
    const int lane = t & 63;

    for (int i = t; i < 128 * FDIM; i += 512) acc[i] = 0.f;
    if (t < 128) cnt[t] = 0;

    if (w == 0) {                        // wave 0: prefix scan of bucket counts
        int carry = 0;
        for (int ch = 0; ch < 7; ++ch) { // 7*64 = 448 >= 392
            int idx = ch * 64 + lane;
            int v = (idx < NBUCK) ? bc_pad[idx * PAD] : 0;
            int sv = v;
#pragma unroll
            for (int off = 1; off < 64; off <<= 1) {
                int u = __shfl_up(sv, off, 64);
                if (lane >= off) sv += u;
            }
            if (idx <= NBUCK) sEx[idx] = carry + sv - v;
            carry += __shfl(sv, 63, 64);
        }
    }
    __syncthreads();

    const int s0 = sEx[blockIdx.x];
    const int e0 = sEx[blockIdx.x + 1];

    const int slot = lane >> 3;          // 0..7 edge slot
    const int c = lane & 7;              // col oct 0..7

#define PROC(pk) do {                                                       \
        int row_ = (int)((pk >> 16) & 127);                                 \
        int src_ = (int)(pk & 0xffffu);                                     \
        uint4 v_ = *(const uint4*)(xb + (size_t)src_ * FDIM + c * 8);       \
        int rb_ = row_ * FDIM;                                              \
        int o_ = (c * 8 + row_) & 63;                                       \
        atomicAdd(&acc[rb_ + ((o_ + 0) & 63)], bf2f_lo(v_.x));              \
        atomicAdd(&acc[rb_ + ((o_ + 1) & 63)], bf2f_hi(v_.x));              \
        atomicAdd(&acc[rb_ + ((o_ + 2) & 63)], bf2f_lo(v_.y));              \
        atomicAdd(&acc[rb_ + ((o_ + 3) & 63)], bf2f_hi(v_.y));              \
        atomicAdd(&acc[rb_ + ((o_ + 4) & 63)], bf2f_lo(v_.z));              \
        atomicAdd(&acc[rb_ + ((o_ + 5) & 63)], bf2f_hi(v_.z));              \
        atomicAdd(&acc[rb_ + ((o_ + 6) & 63)], bf2f_lo(v_.w));              \
        atomicAdd(&acc[rb_ + ((o_ + 7) & 63)], bf2f_hi(v_.w));              \
        if (c == 0) atomicAdd(&cnt[row_], 1);                               \
    } while (0)

    int i = s0 + w * 8 + slot;
    for (; i + 64 < e0; i += 128) {      // 2x unroll: 16 rows in flight/wave
        unsigned pk0 = ebuf[i];
        unsigned pk1 = ebuf[i + 64];
        PROC(pk0);
        PROC(pk1);
    }
    for (; i < e0; i += 64) {
        unsigned pk0 = ebuf[i];
        PROC(pk0);
    }
#undef PROC
    __syncthreads();

    // ---- transform: 128 nodes = 8 groups x 4 col-tiles = 32 tasks / 8 waves ----
    const int node_base = blockIdx.x * 128;
    const int q = lane >> 4;
    const int r = lane & 15;
    const short8* plw = (const short8*)pWl;
    const short8* prw = (const short8*)pWr;

    for (int task = w; task < 32; task += 8) {
        const int grp = task >> 2;       // 0..7
        const int ct = task & 3;         // 0..3
        const int lrow = grp * 16 + r;
        const int node = node_base + lrow;
        const bool valid = node < N_NODES;

        uint4 sx0 = make_uint4(0, 0, 0, 0), sx1 = make_uint4(0, 0, 0, 0);
        if (valid) {
            sx0 = *(const uint4*)(xb + (size_t)node * FDIM + q * 8);
            sx1 = *(const uint4*)(xb + (size_t)node * FDIM + 32 + q * 8);
        }
        const float inv = 1.0f / (float)(cnt[lrow] + 1);
        const int rb = lrow * FDIM;

        float sf0[8] = { bf2f_lo(sx0.x), bf2f_hi(sx0.x), bf2f_lo(sx0.y), bf2f_hi(sx0.y),
                         bf2f_lo(sx0.z), bf2f_hi(sx0.z), bf2f_lo(sx0.w), bf2f_hi(sx0.w) };
        float sf1[8] = { bf2f_lo(sx1.x), bf2f_hi(sx1.x), bf2f_lo(sx1.y), bf2f_hi(sx1.y),
                         bf2f_lo(sx1.z), bf2f_hi(sx1.z), bf2f_lo(sx1.w), bf2f_hi(sx1.w) };

        short8 am0, am1;
#pragma unroll
        for (int j = 0; j < 8; ++j) {
            int col0 = q * 8 + j;
            int col1 = 32 + q * 8 + j;
            float a0 = acc[rb + ((col0 + lrow) & 63)];
            float a1 = acc[rb + ((col1 + lrow) & 63)];
            am0[j] = (short)(unsigned short)f2bf((a0 + sf0[j]) * inv);
            am1[j] = (short)(unsigned short)f2bf((a1 + sf1[j]) * inv);
        }
        short8 ax0 = *(short8*)&sx0;
        short8 ax1 = *(short8*)&sx1;

        short8 bl0v = plw[(ct * 2 + 0) * 64 + lane];
        short8 bl1v = plw[(ct * 2 + 1) * 64 + lane];
        short8 br0v = prw[(ct * 2 + 0) * 64 + lane];
        short8 br1v = prw[(ct * 2 + 1) * 64 + lane];

        float bias = bl[ct * 16 + r];
        f32x4 accv = {bias, bias, bias, bias};
        accv = __builtin_amdgcn_mfma_f32_16x16x32_bf16(am0, bl0v, accv, 0, 0, 0);
        accv = __builtin_amdgcn_mfma_f32_16x16x32_bf16(am1, bl1v, accv, 0, 0, 0);
        accv = __builtin_amdgcn_mfma_f32_16x16x32_bf16(ax0, br0v, accv, 0, 0, 0);
        accv = __builtin_amdgcn_mfma_f32_16x16x32_bf16(ax1, br1v, accv, 0, 0, 0);

#pragma unroll
        for (int reg = 0; reg < 4; ++reg) {
            int node_o = node_base + grp * 16 + q * 4 + reg;
            if (node_o < N_NODES) {
                float v = fmaxf(accv[reg], 0.0f);
                if (OUT_BF16) out_bf[(size_t)node_o * FDIM + ct * 16 + r] = (unsigned short)f2bf(v);
                else          out_f32[(size_t)node_o * FDIM + ct * 16 + r] = v;
            }
        }
    }
}

// ---------------------------------------------------------------------------
extern "C" void kernel_launch(void* const* d_in, const int* in_sizes, int n_in,
                              void* d_out, int out_size, void* d_ws, size_t ws_size,
                              hipStream_t stream) {
    const float* x0  = (const float*)d_in[0];
    const int*   ei  = (const int*)d_in[1];
    const float* Wl0 = (const float*)d_in[2];
    const float* bl0 = (const float*)d_in[3];
    const float* Wr0 = (const float*)d_in[4];
    const float* Wl1 = (const float*)d_in[5];
    const float* bl1 = (const float*)d_in[6];
    const float* Wr1 = (const float*)d_in[7];
    float* out = (float*)d_out;

    const int* src = ei;            // edge_index[0]
    const int* dst = ei + N_EDGES;  // edge_index[1]

    // workspace: bc_pad[6400] | cur_pad[6400] | ebuf[800000] | x_bf | h_bf | pW
    int* bc_pad    = (int*)d_ws;
    int* cur_pad   = bc_pad + 6400;                   // 391*16 = 6256 used
    unsigned* ebuf = (unsigned*)(cur_pad + 6400);
    unsigned short* x_bf = (unsigned short*)(ebuf + N_EDGES);
    unsigned short* h_bf = x_bf + (size_t)N_NODES * FDIM;
    unsigned short* pW   = h_bf + (size_t)N_NODES * FDIM;   // 4 x 4096

    hipMemsetAsync(bc_pad, 0, 2 * 6400 * sizeof(int), stream);
    preprocess_kernel<<<3911, 256, 0, stream>>>(x0, x_bf, Wl0, Wr0, Wl1, Wr1,
                                                pW, dst, bc_pad);
    bucket_scatter_kernel<<<(N_EDGES + 1023) / 1024, 256, 0, stream>>>(
        src, dst, bc_pad, cur_pad, ebuf);

    // ---- layer 0 (bf16 out) ----
    sage_accum_kernel<true><<<NBUCK, 512, 0, stream>>>(
        x_bf, ebuf, bc_pad, pW + 0 * FDIM * FDIM, bl0, pW + 1 * FDIM * FDIM,
        nullptr, h_bf);
    // ---- layer 1 (fp32 out) ----
    sage_accum_kernel<false><<<NBUCK, 512, 0, stream>>>(
        h_bf, ebuf, bc_pad, pW + 2 * FDIM * FDIM, bl1, pW + 3 * FDIM * FDIM,
        out, nullptr);
}

// Round 13
// 156.747 us; speedup vs baseline: 5.3523x; 5.3523x over previous
//
#include <hip/hip_runtime.h>
#include <hip/hip_bf16.h>

#define N_NODES 50000
#define N_EDGES 800000
#define FDIM 64
#define NBUCK 196          // ceil(50000/256) buckets of 256 nodes
#define CAP 4608           // per-bucket edge capacity: mean 4096 + 8 sigma
#define PAD 16             // one counter per 64B line

typedef __attribute__((ext_vector_type(8))) short short8;
typedef __attribute__((ext_vector_type(4))) float f32x4;

// fp32 -> bf16 bits, round-to-nearest-even
__device__ __forceinline__ unsigned f2bf(float f) {
    unsigned u = __float_as_uint(f);
    u += 0x7fffu + ((u >> 16) & 1u);
    return u >> 16;
}
__device__ __forceinline__ float bf2f_lo(unsigned u) { return __uint_as_float(u << 16); }
__device__ __forceinline__ float bf2f_hi(unsigned u) { return __uint_as_float(u & 0xffff0000u); }

// exclusive scan of one value per thread across a 256-thread block
__device__ __forceinline__ int excl_scan_256(int v, int* wtot, int* wincl) {
    const int t = threadIdx.x, lane = t & 63, w = t >> 6;
    int sv = v;
#pragma unroll
    for (int off = 1; off < 64; off <<= 1) {
        int u = __shfl_up(sv, off, 64);
        if (lane >= off) sv += u;
    }
    if (lane == 63) wtot[w] = sv;
    __syncthreads();
    if (w == 0 && lane < 4) {
        int incl = 0;
#pragma unroll
        for (int k = 0; k < 4; ++k)
            if (k <= lane) incl += wtot[k];
        wincl[lane] = incl;
    }
    __syncthreads();
    return (w ? wincl[w - 1] : 0) + sv - v;
}

// ---------------------------------------------------------------------------
// preprocess (fused): [0,3124] convert x0->bf16; [3125,3128] pack weights into
// MFMA B-fragment order; [3129] zero bucket cursors. No histogram needed
// (fixed-capacity buckets).
// ---------------------------------------------------------------------------
__global__ __launch_bounds__(256)
void preprocess_kernel(const float* __restrict__ x0, unsigned short* __restrict__ x_bf,
                       const float* __restrict__ Wl0, const float* __restrict__ Wr0,
                       const float* __restrict__ Wl1, const float* __restrict__ Wr1,
                       unsigned short* __restrict__ pW, int* __restrict__ cur_pad) {
    const int b = blockIdx.x;
    const int t = threadIdx.x;
    if (b < 3125) {                       // convert: 3125*256*4 = 3.2M exactly
        int i = (b * 256 + t) * 4;
        float4 v = *(const float4*)(x0 + i);
        uint2 o;
        o.x = f2bf(v.x) | (f2bf(v.y) << 16);
        o.y = f2bf(v.z) | (f2bf(v.w) << 16);
        *(uint2*)(x_bf + i) = o;
    } else if (b < 3129) {                // pack W into MFMA B-fragment order
        const float* Wsrc[4] = {Wl0, Wr0, Wl1, Wr1};
        const float* W = Wsrc[b - 3125];
        unsigned short* P = pW + (b - 3125) * FDIM * FDIM;
        for (int idx = t; idx < FDIM * FDIM; idx += 256) {
            int j = idx & 7;
            int lane = (idx >> 3) & 63;
            int g = idx >> 9;             // ct*2 + kk
            int ct = g >> 1, kk = g & 1;
            int k = kk * 32 + ((lane >> 4) & 3) * 8 + j;
            int col = ct * 16 + (lane & 15);
            P[idx] = (unsigned short)f2bf(W[k * FDIM + col]);
        }
    } else {                              // zero bucket cursors
        if (t < NBUCK) cur_pad[t * PAD] = 0;
    }
}

// ---------------------------------------------------------------------------
// bucket scatter (no pre-histogram): rank edges per bucket in LDS, reserve
// space in the bucket's FIXED region [bk*CAP, ...) with one padded global
// atomic per (block,bucket), write packed (dst<<16)|src.
// ---------------------------------------------------------------------------
__global__ __launch_bounds__(256)
void bucket_scatter_kernel(const int* __restrict__ src, const int* __restrict__ dst,
                           int* __restrict__ cur_pad, unsigned* __restrict__ ebuf) {
    __shared__ int h[NBUCK];
    __shared__ int base[NBUCK];
    const int t = threadIdx.x;

    if (t < NBUCK) h[t] = 0;
    __syncthreads();

    int e0 = blockIdx.x * 1024;
    int bk[4], rk[4]; unsigned pk[4];
#pragma unroll
    for (int k = 0; k < 4; ++k) {
        int e = e0 + k * 256 + t;
        if (e < N_EDGES) {
            int d = dst[e];
            bk[k] = d >> 8;
            pk[k] = ((unsigned)d << 16) | (unsigned)src[e];
            rk[k] = atomicAdd(&h[bk[k]], 1);
        } else bk[k] = -1;
    }
    __syncthreads();
    if (t < NBUCK) {
        int c = h[t];
        base[t] = c ? (t * CAP + atomicAdd(&cur_pad[t * PAD], c)) : 0;
    }
    __syncthreads();
#pragma unroll
    for (int k = 0; k < 4; ++k)
        if (bk[k] >= 0) ebuf[base[bk[k]] + rk[k]] = pk[k];
}

// ---------------------------------------------------------------------------
// bucket CSR finalize: one block per bucket (256 nodes). LDS histogram of
// dst&255 -> scan -> row_start (absolute, bucket-padded csr) + deg (u16);
// LDS-cursor scatter of src u16 into the bucket's contiguous window.
// ---------------------------------------------------------------------------
__global__ __launch_bounds__(256)
void bucket_csr_kernel(const unsigned* __restrict__ ebuf, const int* __restrict__ cur_pad,
                       int* __restrict__ row_start, unsigned short* __restrict__ degs,
                       unsigned short* __restrict__ csr) {
    __shared__ int cnt[256];
    __shared__ int cur[256];
    __shared__ int wtot[4], wincl[4];
    const int b = blockIdx.x;
    const int t = threadIdx.x;
    const int s = b * CAP;
    const int e = s + cur_pad[b * PAD];

    cnt[t] = 0;
    __syncthreads();
    for (int i = s + t; i < e; i += 256)
        atomicAdd(&cnt[(ebuf[i] >> 16) & 255], 1);
    __syncthreads();

    int c = cnt[t];
    int ex = excl_scan_256(c, wtot, wincl);
    cur[t] = ex;
    int node = b * 256 + t;
    if (node < N_NODES) {
        row_start[node] = s + ex;
        degs[node] = (unsigned short)c;
    }
    __syncthreads();

    for (int i = s + t; i < e; i += 256) {
        unsigned pk = ebuf[i];
        int pos = s + atomicAdd(&cur[(pk >> 16) & 255], 1);
        csr[pos] = (unsigned short)pk;
    }
}

// ---------------------------------------------------------------------------
// fused SAGE layer, slot-parallel gather. Block = 128 (2 waves), 16 nodes.
// Gather: wave = 8 slots x 8 lanes; slot owns node r = w*8+slot, lane covers
//   col-oct c; walks its own edge list (uniform in slot) with 4 rows in
//   flight; NO cross-lane reduction. mean+self staged in LDS bf16, octs
//   XOR-swizzled by row&7 (round-10-verified pattern).
// MFMA: wave w does col-tiles 2w,2w+1. A[m=lane&15][k=(lane>>4)*8+j];
//   C/D: col=lane&15, row=(lane>>4)*4+reg. Grid 3125 (x16 = 50000 exactly).
// ---------------------------------------------------------------------------
template <bool OUT_BF16>
__global__ __launch_bounds__(128)
void sage_fused_kernel(const unsigned short* __restrict__ xb,
                       const int* __restrict__ row_start,
                       const unsigned short* __restrict__ degs,
                       const unsigned short* __restrict__ csr,
                       const unsigned short* __restrict__ pWl,
                       const float* __restrict__ bl,
                       const unsigned short* __restrict__ pWr,
                       float* __restrict__ out_f32,
                       unsigned short* __restrict__ out_bf) {
    __shared__ __align__(16) unsigned short smean[16][FDIM];
    __shared__ __align__(16) unsigned short sxs[16][FDIM];

    const int w = threadIdx.x >> 6;       // 0..1
    const int lane = threadIdx.x & 63;
    const int slot = lane >> 3;           // 0..7 -> node within wave
    const int c = lane & 7;               // col-oct 0..7
    const int base = blockIdx.x * 16;
    const int r = w * 8 + slot;           // local row 0..15
    const int n = base + r;

    const int rs = row_start[n];
    const int deg = degs[n];
    const int po = (c ^ (r & 7)) * 8;     // swizzled physical oct offset

    // self row: stage to LDS + seed accumulator
    uint4 sv = *(const uint4*)(xb + (size_t)n * FDIM + c * 8);
    *(uint4*)(&sxs[r][po]) = sv;
    float s0 = bf2f_lo(sv.x), s1 = bf2f_hi(sv.x);
    float s2 = bf2f_lo(sv.y), s3 = bf2f_hi(sv.y);
    float s4 = bf2f_lo(sv.z), s5 = bf2f_hi(sv.z);
    float s6 = bf2f_lo(sv.w), s7 = bf2f_hi(sv.w);

#define ACC(v_) do {                                   \
        s0 += bf2f_lo(v_.x); s1 += bf2f_hi(v_.x);      \
        s2 += bf2f_lo(v_.y); s3 += bf2f_hi(v_.y);      \
        s4 += bf2f_lo(v_.z); s5 += bf2f_hi(v_.z);      \
        s6 += bf2f_lo(v_.w); s7 += bf2f_hi(v_.w);      \
    } while (0)

    int idx = rs;
    int rem = deg;
    while (rem >= 4) {                    // 4 rows in flight per slot
        int a0 = csr[idx + 0];
        int a1 = csr[idx + 1];
        int a2 = csr[idx + 2];
        int a3 = csr[idx + 3];
        uint4 v0 = *(const uint4*)(xb + (size_t)a0 * FDIM + c * 8);
        uint4 v1 = *(const uint4*)(xb + (size_t)a1 * FDIM + c * 8);
        uint4 v2 = *(const uint4*)(xb + (size_t)a2 * FDIM + c * 8);
        uint4 v3 = *(const uint4*)(xb + (size_t)a3 * FDIM + c * 8);
        ACC(v0); ACC(v1); ACC(v2); ACC(v3);
        idx += 4; rem -= 4;
    }
    while (rem > 0) {
        int a0 = csr[idx];
        uint4 v0 = *(const uint4*)(xb + (size_t)a0 * FDIM + c * 8);
        ACC(v0);
        ++idx; --rem;
    }
#undef ACC

    const float inv = 1.0f / (float)(deg + 1);
    uint4 o;
    o.x = f2bf(s0 * inv) | (f2bf(s1 * inv) << 16);
    o.y = f2bf(s2 * inv) | (f2bf(s3 * inv) << 16);
    o.z = f2bf(s4 * inv) | (f2bf(s5 * inv) << 16);
    o.w = f2bf(s6 * inv) | (f2bf(s7 * inv) << 16);
    *(uint4*)(&smean[r][po]) = o;
    __syncthreads();

    // ---- MFMA phase: wave w -> col-tiles 2w, 2w+1 ----
    const int qq = lane >> 4;
    const int rr = lane & 15;

    short8 am0 = *(const short8*)(&smean[rr][((0 + qq) ^ (rr & 7)) * 8]);
    short8 am1 = *(const short8*)(&smean[rr][((4 + qq) ^ (rr & 7)) * 8]);
    short8 ax0 = *(const short8*)(&sxs[rr][((0 + qq) ^ (rr & 7)) * 8]);
    short8 ax1 = *(const short8*)(&sxs[rr][((4 + qq) ^ (rr & 7)) * 8]);

    const short8* pl = (const short8*)pWl;
    const short8* pr = (const short8*)pWr;

#pragma unroll
    for (int tk = 0; tk < 2; ++tk) {
        const int ct = w * 2 + tk;
        short8 bl0v = pl[(ct * 2 + 0) * 64 + lane];
        short8 bl1v = pl[(ct * 2 + 1) * 64 + lane];
        short8 br0v = pr[(ct * 2 + 0) * 64 + lane];
        short8 br1v = pr[(ct * 2 + 1) * 64 + lane];

        float b = bl[ct * 16 + rr];
        f32x4 acc = {b, b, b, b};
        acc = __builtin_amdgcn_mfma_f32_16x16x32_bf16(am0, bl0v, acc, 0, 0, 0);
        acc = __builtin_amdgcn_mfma_f32_16x16x32_bf16(am1, bl1v, acc, 0, 0, 0);
        acc = __builtin_amdgcn_mfma_f32_16x16x32_bf16(ax0, br0v, acc, 0, 0, 0);
        acc = __builtin_amdgcn_mfma_f32_16x16x32_bf16(ax1, br1v, acc, 0, 0, 0);

#pragma unroll
        for (int reg = 0; reg < 4; ++reg) {
            int node = base + qq * 4 + reg;
            float v = fmaxf(acc[reg], 0.0f);
            if (OUT_BF16) out_bf[(size_t)node * FDIM + ct * 16 + rr] = (unsigned short)f2bf(v);
            else          out_f32[(size_t)node * FDIM + ct * 16 + rr] = v;
        }
    }
}

// ---------------------------------------------------------------------------
extern "C" void kernel_launch(void* const* d_in, const int* in_sizes, int n_in,
                              void* d_out, int out_size, void* d_ws, size_t ws_size,
                              hipStream_t stream) {
    const float* x0  = (const float*)d_in[0];
    const int*   ei  = (const int*)d_in[1];
    const float* Wl0 = (const float*)d_in[2];
    const float* bl0 = (const float*)d_in[3];
    const float* Wr0 = (const float*)d_in[4];
    const float* Wl1 = (const float*)d_in[5];
    const float* bl1 = (const float*)d_in[6];
    const float* Wr1 = (const float*)d_in[7];
    float* out = (float*)d_out;

    const int* src = ei;            // edge_index[0]
    const int* dst = ei + N_EDGES;  // edge_index[1]

    // workspace layout (all segments 16B-aligned by construction):
    // cur_pad[3136] | row_start[50000] | degs u16[50000] | ebuf[196*4608] |
    // csr u16[196*4608] | x_bf | h_bf | pW(4x4096)
    int* cur_pad    = (int*)d_ws;                        // 3136 ints
    int* row_start  = cur_pad + 3136;                    // 50000 ints
    unsigned short* degs = (unsigned short*)(row_start + 50000);   // 50000
    unsigned* ebuf  = (unsigned*)(degs + 50000);         // 903168 uints
    unsigned short* csr_u16 = (unsigned short*)(ebuf + NBUCK * CAP);  // 903168
    unsigned short* x_bf = csr_u16 + NBUCK * CAP;
    unsigned short* h_bf = x_bf + (size_t)N_NODES * FDIM;
    unsigned short* pW   = h_bf + (size_t)N_NODES * FDIM;   // 4 x 4096

    preprocess_kernel<<<3130, 256, 0, stream>>>(x0, x_bf, Wl0, Wr0, Wl1, Wr1,
                                                pW, cur_pad);
    bucket_scatter_kernel<<<(N_EDGES + 1023) / 1024, 256, 0, stream>>>(
        src, dst, cur_pad, ebuf);
    bucket_csr_kernel<<<NBUCK, 256, 0, stream>>>(ebuf, cur_pad, row_start, degs, csr_u16);

    // ---- layer 0 (bf16 out) ----
    sage_fused_kernel<true><<<N_NODES / 16, 128, 0, stream>>>(
        x_bf, row_start, degs, csr_u16, pW + 0 * FDIM * FDIM, bl0,
        pW + 1 * FDIM * FDIM, nullptr, h_bf);
    // ---- layer 1 (fp32 out) ----
    sage_fused_kernel<false><<<N_NODES / 16, 128, 0, stream>>>(
        h_bf, row_start, degs, csr_u16, pW + 2 * FDIM * FDIM, bl1,
        pW + 3 * FDIM * FDIM, out, nullptr);
}